// Round 14
// baseline (359.770 us; speedup 1.0000x reference)
//
#include <hip/hip_runtime.h>
#include <hip/hip_fp16.h>
#include <math.h>

#define TAU 0.5f   // |pivot|^2 threshold (f32) for the fast pivot path

// ---------------------------------------------------------------------------
// Fused kernel: 2306 blocks x 256 threads (structure = round 12).
//   bid % 9 == 8 (bid<2304)  -> conv block  cid = bid/9        (256 blocks)
//   else                     -> logdet block, key = lid        (2050 blocks)
//
// Round-14 delta (logdet inner loop only): pivot-row broadcast moves from
// per-element v_readlane (~2000/wave @ ~12 issue-cyc = half the wave's
// cycles) to a per-step LDS round-trip: pivot lane packs slots 1..rem into
// int4s and ds_write_b128s them to a private 256B wave slice; all lanes
// then broadcast-ds_read_b128 4 columns per issue. ~1000 DS issues/matrix
// total (r8's failed bpermute variant was ~8000 single-element DS ops).
// Same-wave DS ordering makes write->read safe without barriers.
// r13's SALU swap reverted: __lowhigh2highlow folds into pk_fma op_sel.
// ---------------------------------------------------------------------------
__device__ __forceinline__ int h2i(__half2 h) { int i; __builtin_memcpy(&i, &h, 4); return i; }
__device__ __forceinline__ __half2 i2h(int i) { __half2 h; __builtin_memcpy(&h, &i, 4); return h; }

__global__ __launch_bounds__(256, 2) void fused_kernel(
    const float* __restrict__ x, const float* __restrict__ K,
    const float* __restrict__ bias, float* __restrict__ out,
    float* __restrict__ logdet) {
  __shared__ float smem[4736];               // conv: w[576]+tile[64*65]; logdet: 4x64 ints
  int bid = blockIdx.x;
  int t = threadIdx.x;

  bool isConv = false;
  int cid = 0, lid = 0;
  if (bid < 2304) {
    int q9 = bid / 9, m9 = bid - q9 * 9;
    if (m9 == 8) { isConv = true; cid = q9; }
    else lid = bid - (bid + 1) / 9;          // 0..2047
  } else {
    lid = bid - 256;                         // 2048, 2049
  }

  if (isConv) {
    // ================= conv =================
    int b = cid >> 6, co = cid & 63;
    float* w = smem;                         // 576
    float* tile = smem + 576;                // 64*65

    for (int i = t; i < 576; i += 256) {
      float vv = K[(size_t)((b * 64 + co) * 64) * 9 + i];
      if (i == co * 9 + 4) vv += 1.0f;       // identity: ci==co, center tap
      w[i] = vv;
    }

    int ty = t >> 2;
    int tx = t & 3;
    int x0 = tx << 4;
    float bval = bias[b * 64 + co];
    float acc[16];
#pragma unroll
    for (int i = 0; i < 16; ++i) acc[i] = bval;

    const float* xb = x + (size_t)(b * 64) * 4096;
    for (int ci = 0; ci < 64; ++ci) {
      __syncthreads();                       // WAR on tile (and w on first iter)
      const float* xc = xb + (size_t)ci * 4096;
#pragma unroll
      for (int j = 0; j < 16; ++j) {
        int i = t + 256 * j;
        tile[(i >> 6) * 65 + (i & 63)] = xc[i];
      }
      __syncthreads();

      float w0 = w[ci * 9 + 0], w1 = w[ci * 9 + 1], w2 = w[ci * 9 + 2];
      float w3 = w[ci * 9 + 3], w4 = w[ci * 9 + 4], w5 = w[ci * 9 + 5];
      float w6 = w[ci * 9 + 6], w7 = w[ci * 9 + 7], w8 = w[ci * 9 + 8];

      int ym = ((ty - 1) & 63) * 65;
      int yc = ty * 65;
      int yp = ((ty + 1) & 63) * 65;
      float in0[18], in1[18], in2[18];
#pragma unroll
      for (int ix = 0; ix < 18; ++ix) {
        int xx = (x0 + ix - 1) & 63;
        in0[ix] = tile[ym + xx];
        in1[ix] = tile[yc + xx];
        in2[ix] = tile[yp + xx];
      }
#pragma unroll
      for (int px = 0; px < 16; ++px) {
        float a = acc[px];
        a = fmaf(w0, in0[px], a); a = fmaf(w1, in0[px + 1], a); a = fmaf(w2, in0[px + 2], a);
        a = fmaf(w3, in1[px], a); a = fmaf(w4, in1[px + 1], a); a = fmaf(w5, in1[px + 2], a);
        a = fmaf(w6, in2[px], a); a = fmaf(w7, in2[px + 1], a); a = fmaf(w8, in2[px + 2], a);
        acc[px] = a;
      }
    }

    float* op = out + (size_t)(b * 64 + co) * 4096 + ty * 64 + x0;
#pragma unroll
    for (int i = 0; i < 16; i += 4) {
      *(float4*)(op + i) = make_float4(acc[i], acc[i + 1], acc[i + 2], acc[i + 3]);
    }
    return;
  }

  // ================= logdet =================
  int u, v;
  if (lid < 33) { u = 0; v = lid; }
  else if (lid < 2017) { int q = lid - 33; u = 1 + (q >> 6); v = q & 63; }
  else { u = 32; v = lid - 2017; }
  float weight = (((u & 31) == 0) && ((v & 31) == 0)) ? 1.0f : 2.0f;

  int b = t >> 6;                            // wave id == batch
  int r = t & 63;                            // lane == matrix row
  int* lbuf = ((int*)smem) + (b << 6);       // private 64-word slice per wave

  // twiddles w[kh*3+kw] = e^{-2*pi*i*(u*kh+v*kw)/64} via complex power products
  float Ar[3], Ai[3], Br[3], Bi[3];
  {
    const float k2pi = -6.283185307179586f / 64.0f;
    float su, cu, sv, cv;
    __sincosf(k2pi * (float)u, &su, &cu);
    __sincosf(k2pi * (float)v, &sv, &cv);
    Ar[0] = 1.0f; Ai[0] = 0.0f; Ar[1] = cu; Ai[1] = su;
    Ar[2] = cu * cu - su * su; Ai[2] = 2.0f * cu * su;
    Br[0] = 1.0f; Bi[0] = 0.0f; Br[1] = cv; Bi[1] = sv;
    Br[2] = cv * cv - sv * sv; Bi[2] = 2.0f * cv * sv;
  }
  float wr[9], wi[9];
#pragma unroll
  for (int kh = 0; kh < 3; ++kh)
#pragma unroll
    for (int kw = 0; kw < 3; ++kw) {
      wr[kh * 3 + kw] = Ar[kh] * Br[kw] - Ai[kh] * Bi[kw];
      wi[kh * 3 + kw] = Ar[kh] * Bi[kw] + Ai[kh] * Br[kw];
    }

  // Build row r of Khat in fp32, pack each column to f16x2 immediately.
  __half2 a2[65];
  const float4* Kp4 = (const float4*)(K + (size_t)(b * 64 + r) * 576);
#pragma unroll
  for (int g = 0; g < 16; ++g) {             // 16 groups x 4 columns
    float f[36];
#pragma unroll
    for (int qq = 0; qq < 9; ++qq) {
      float4 vv = Kp4[g * 9 + qq];
      f[qq * 4 + 0] = vv.x; f[qq * 4 + 1] = vv.y; f[qq * 4 + 2] = vv.z; f[qq * 4 + 3] = vv.w;
    }
#pragma unroll
    for (int cc = 0; cc < 4; ++cc) {
      int c = g * 4 + cc;
      float re = 0.0f, im = 0.0f;
#pragma unroll
      for (int t9 = 0; t9 < 9; ++t9) {
        float kv = f[cc * 9 + t9];
        re = fmaf(kv, wr[t9], re);
        im = fmaf(kv, wi[t9], im);
      }
      if (c == r) { re += wr[4]; im += wi[4]; }  // identity: center-tap delta
      a2[c] = __floats2half2_rn(re, im);
    }
  }
  a2[64] = __floats2half2_rn(0.0f, 0.0f);    // pad slot for chunk overshoot

  bool active = true;
  float pivmag = 1.0f;                       // each lane's own pivot |.|^2 (f32)

  for (int k = 0; k < 63; ++k) {
    float fr0 = __low2float(a2[0]);
    float fi0 = __high2float(a2[0]);
    float mag = fmaf(fr0, fr0, fi0 * fi0);
    bool cand = active && (mag >= TAU);
    unsigned long long candm = __ballot(cand);
    int p;
    if (candm != 0ULL) {
      p = __ffsll(candm) - 1;                // fast path: first big-enough pivot
    } else {                                 // rare: all remaining pivots tiny
      float mm = active ? mag : -1.0f;
#pragma unroll
      for (int off = 32; off > 0; off >>= 1) mm = fmaxf(mm, __shfl_xor(mm, off));
      unsigned long long mx = __ballot(active && (mag == mm));
      if (mx == 0ULL) mx = __ballot(active); // degenerate (NaN) guard
      p = __ffsll(mx) - 1;
    }
    p &= 63;                                 // uniform (ballot-derived), valid lane

    int rem = 63 - k;                        // remaining columns at slots 1..rem

    // pivot lane publishes its trailing row (slots 1..rem) to the wave slice:
    // packed int4 -> ds_write_b128, ~2*ceil(rem/8) issues.
    if (r == p) {
#pragma unroll
      for (int ch = 0; ch < 8; ++ch) {
        if (ch * 8 < rem) {                  // uniform scalar guard
          int c0 = ch * 8 + 1;
          ((int4*)lbuf)[ch * 2 + 0] = make_int4(
              h2i(a2[c0 + 0]), h2i(a2[c0 + 1]), h2i(a2[c0 + 2]), h2i(a2[c0 + 3]));
          ((int4*)lbuf)[ch * 2 + 1] = make_int4(
              h2i(a2[c0 + 4]), h2i(a2[c0 + 5]), h2i(a2[c0 + 6]), h2i(a2[c0 + 7]));
        }
      }
    }

    bool isPiv = (r == p);
    pivmag = isPiv ? mag : pivmag;           // latch; log deferred to the end
    active = active && !isPiv;

    __half2 pivh = i2h(__builtin_amdgcn_readlane(h2i(a2[0]), p));
    float pr = __low2float(pivh);
    float pi = __high2float(pivh);
    float inv = __builtin_amdgcn_rcpf(fmaf(pr, pr, pi * pi));
    float fre = (fr0 * pr + fi0 * pi) * inv;
    float fim = (fi0 * pr - fr0 * pi) * inv;
    fre = active ? fre : 0.0f;               // pivot + retired lanes: shift-only
    fim = active ? fim : 0.0f;
    __half2 nfre2 = __float2half2_rn(-fre);                     // (-fre, -fre)
    __half2 fim2 = __halves2half2(__float2half_rn(fim),
                                  __float2half_rn(-fim));       // (fim, -fim)

    // broadcast ds_read_b128: 4 columns per issue, conflict-free.
#pragma unroll
    for (int ch = 0; ch < 8; ++ch) {
      if (ch * 8 < rem) {                    // uniform scalar guard, chunk=8
        int c0 = ch * 8 + 1;
        int4 La = ((const int4*)lbuf)[ch * 2 + 0];
        int4 Lb = ((const int4*)lbuf)[ch * 2 + 1];
        int Li[8] = {La.x, La.y, La.z, La.w, Lb.x, Lb.y, Lb.z, Lb.w};
#pragma unroll
        for (int e = 0; e < 8; ++e) {
          __half2 P = i2h(Li[e]);
          // (re',im') = (re,im) - fre*(lr,li) + fim*(li,-lr): 2 pk_fma
          // (__lowhigh2highlow folds into pk_fma op_sel -- r13 errata)
          __half2 tmp = __hfma2(nfre2, P, a2[c0 + e]);
          a2[c0 + e - 1] = __hfma2(fim2, __lowhigh2highlow(P), tmp);
        }
      }
    }
  }
  {
    float fr0 = __low2float(a2[0]);
    float fi0 = __high2float(a2[0]);
    if (active) pivmag = fmaf(fr0, fr0, fi0 * fi0);  // last surviving row
  }

  float logsum = 0.5f * __logf(pivmag);      // one log per lane; sum = logdet
#pragma unroll
  for (int off = 32; off > 0; off >>= 1) logsum += __shfl_xor(logsum, off);
  if (r == 0) atomicAdd(&logdet[b], weight * logsum);
}

// ---------------------------------------------------------------------------
extern "C" void kernel_launch(void* const* d_in, const int* in_sizes, int n_in,
                              void* d_out, int out_size, void* d_ws, size_t ws_size,
                              hipStream_t stream) {
  const float* conv_in = (const float*)d_in[0];   // [4,64,64,64]
  const float* K       = (const float*)d_in[1];   // [4,64,64,3,3]
  const float* bias    = (const float*)d_in[2];   // [4,64,1,1]
  float* out = (float*)d_out;                     // conv_out (1048576) ++ logdet (4)
  float* logdet = out + 1048576;

  hipMemsetAsync(logdet, 0, 4 * sizeof(float), stream);
  fused_kernel<<<dim3(2306), dim3(256), 0, stream>>>(conv_in, K, bias, out, logdet);
}

// Round 15
// 335.732 us; speedup vs baseline: 1.0716x; 1.0716x over previous
//
#include <hip/hip_runtime.h>
#include <hip/hip_fp16.h>
#include <math.h>

#define TAU 0.5f   // |pivot|^2 threshold (f32) for the fast pivot path

// ---------------------------------------------------------------------------
// Fused kernel: 2306 blocks x 256 threads (structure = round 12).
//   bid % 9 == 8 (bid<2304)  -> conv block  cid = bid/9        (256 blocks)
//   else                     -> logdet block, key = lid        (2050 blocks)
//
// Round-15 delta: __launch_bounds__(256, 3) -> 3 blocks/CU (12 waves/CU).
// r12 at 2 blocks/CU ran 59% VALUBusy: single-wave readlane->pk_fma chains
// leave ~40% issue slots idle; a third co-resident block fills them.
// VGPR headroom ample (76 used, ~170 cap); LDS 3x18.9KB < 160KB.
// Inner loop = r12 verbatim (readlane broadcast, op_sel-folded swap):
// r8/r13/r14 established DS-pipe broadcasts and SALU swaps both regress.
// ---------------------------------------------------------------------------
__device__ __forceinline__ int h2i(__half2 h) { int i; __builtin_memcpy(&i, &h, 4); return i; }
__device__ __forceinline__ __half2 i2h(int i) { __half2 h; __builtin_memcpy(&h, &i, 4); return h; }

__global__ __launch_bounds__(256, 3) void fused_kernel(
    const float* __restrict__ x, const float* __restrict__ K,
    const float* __restrict__ bias, float* __restrict__ out,
    float* __restrict__ logdet) {
  __shared__ float smem[4736];               // conv: w[576] + tile[64*65]
  int bid = blockIdx.x;
  int t = threadIdx.x;

  bool isConv = false;
  int cid = 0, lid = 0;
  if (bid < 2304) {
    int q9 = bid / 9, m9 = bid - q9 * 9;
    if (m9 == 8) { isConv = true; cid = q9; }
    else lid = bid - (bid + 1) / 9;          // 0..2047
  } else {
    lid = bid - 256;                         // 2048, 2049
  }

  if (isConv) {
    // ================= conv =================
    int b = cid >> 6, co = cid & 63;
    float* w = smem;                         // 576
    float* tile = smem + 576;                // 64*65

    for (int i = t; i < 576; i += 256) {
      float vv = K[(size_t)((b * 64 + co) * 64) * 9 + i];
      if (i == co * 9 + 4) vv += 1.0f;       // identity: ci==co, center tap
      w[i] = vv;
    }

    int ty = t >> 2;
    int tx = t & 3;
    int x0 = tx << 4;
    float bval = bias[b * 64 + co];
    float acc[16];
#pragma unroll
    for (int i = 0; i < 16; ++i) acc[i] = bval;

    const float* xb = x + (size_t)(b * 64) * 4096;
    for (int ci = 0; ci < 64; ++ci) {
      __syncthreads();                       // WAR on tile (and w on first iter)
      const float* xc = xb + (size_t)ci * 4096;
#pragma unroll
      for (int j = 0; j < 16; ++j) {
        int i = t + 256 * j;
        tile[(i >> 6) * 65 + (i & 63)] = xc[i];
      }
      __syncthreads();

      float w0 = w[ci * 9 + 0], w1 = w[ci * 9 + 1], w2 = w[ci * 9 + 2];
      float w3 = w[ci * 9 + 3], w4 = w[ci * 9 + 4], w5 = w[ci * 9 + 5];
      float w6 = w[ci * 9 + 6], w7 = w[ci * 9 + 7], w8 = w[ci * 9 + 8];

      int ym = ((ty - 1) & 63) * 65;
      int yc = ty * 65;
      int yp = ((ty + 1) & 63) * 65;
      float in0[18], in1[18], in2[18];
#pragma unroll
      for (int ix = 0; ix < 18; ++ix) {
        int xx = (x0 + ix - 1) & 63;
        in0[ix] = tile[ym + xx];
        in1[ix] = tile[yc + xx];
        in2[ix] = tile[yp + xx];
      }
#pragma unroll
      for (int px = 0; px < 16; ++px) {
        float a = acc[px];
        a = fmaf(w0, in0[px], a); a = fmaf(w1, in0[px + 1], a); a = fmaf(w2, in0[px + 2], a);
        a = fmaf(w3, in1[px], a); a = fmaf(w4, in1[px + 1], a); a = fmaf(w5, in1[px + 2], a);
        a = fmaf(w6, in2[px], a); a = fmaf(w7, in2[px + 1], a); a = fmaf(w8, in2[px + 2], a);
        acc[px] = a;
      }
    }

    float* op = out + (size_t)(b * 64 + co) * 4096 + ty * 64 + x0;
#pragma unroll
    for (int i = 0; i < 16; i += 4) {
      *(float4*)(op + i) = make_float4(acc[i], acc[i + 1], acc[i + 2], acc[i + 3]);
    }
    return;
  }

  // ================= logdet =================
  int u, v;
  if (lid < 33) { u = 0; v = lid; }
  else if (lid < 2017) { int q = lid - 33; u = 1 + (q >> 6); v = q & 63; }
  else { u = 32; v = lid - 2017; }
  float weight = (((u & 31) == 0) && ((v & 31) == 0)) ? 1.0f : 2.0f;

  int b = t >> 6;                            // wave id == batch
  int r = t & 63;                            // lane == matrix row

  // twiddles w[kh*3+kw] = e^{-2*pi*i*(u*kh+v*kw)/64} via complex power products
  float Ar[3], Ai[3], Br[3], Bi[3];
  {
    const float k2pi = -6.283185307179586f / 64.0f;
    float su, cu, sv, cv;
    __sincosf(k2pi * (float)u, &su, &cu);
    __sincosf(k2pi * (float)v, &sv, &cv);
    Ar[0] = 1.0f; Ai[0] = 0.0f; Ar[1] = cu; Ai[1] = su;
    Ar[2] = cu * cu - su * su; Ai[2] = 2.0f * cu * su;
    Br[0] = 1.0f; Bi[0] = 0.0f; Br[1] = cv; Bi[1] = sv;
    Br[2] = cv * cv - sv * sv; Bi[2] = 2.0f * cv * sv;
  }
  float wr[9], wi[9];
#pragma unroll
  for (int kh = 0; kh < 3; ++kh)
#pragma unroll
    for (int kw = 0; kw < 3; ++kw) {
      wr[kh * 3 + kw] = Ar[kh] * Br[kw] - Ai[kh] * Bi[kw];
      wi[kh * 3 + kw] = Ar[kh] * Bi[kw] + Ai[kh] * Br[kw];
    }

  // Build row r of Khat in fp32, pack each column to f16x2 immediately.
  __half2 a2[65];
  const float4* Kp4 = (const float4*)(K + (size_t)(b * 64 + r) * 576);
#pragma unroll
  for (int g = 0; g < 16; ++g) {             // 16 groups x 4 columns
    float f[36];
#pragma unroll
    for (int qq = 0; qq < 9; ++qq) {
      float4 vv = Kp4[g * 9 + qq];
      f[qq * 4 + 0] = vv.x; f[qq * 4 + 1] = vv.y; f[qq * 4 + 2] = vv.z; f[qq * 4 + 3] = vv.w;
    }
#pragma unroll
    for (int cc = 0; cc < 4; ++cc) {
      int c = g * 4 + cc;
      float re = 0.0f, im = 0.0f;
#pragma unroll
      for (int t9 = 0; t9 < 9; ++t9) {
        float kv = f[cc * 9 + t9];
        re = fmaf(kv, wr[t9], re);
        im = fmaf(kv, wi[t9], im);
      }
      if (c == r) { re += wr[4]; im += wi[4]; }  // identity: center-tap delta
      a2[c] = __floats2half2_rn(re, im);
    }
  }
  a2[64] = __floats2half2_rn(0.0f, 0.0f);    // pad slot for chunk overshoot

  bool active = true;
  float pivmag = 1.0f;                       // each lane's own pivot |.|^2 (f32)

  for (int k = 0; k < 63; ++k) {
    float fr0 = __low2float(a2[0]);
    float fi0 = __high2float(a2[0]);
    float mag = fmaf(fr0, fr0, fi0 * fi0);
    bool cand = active && (mag >= TAU);
    unsigned long long candm = __ballot(cand);
    int p;
    if (candm != 0ULL) {
      p = __ffsll(candm) - 1;                // fast path: first big-enough pivot
    } else {                                 // rare: all remaining pivots tiny
      float mm = active ? mag : -1.0f;
#pragma unroll
      for (int off = 32; off > 0; off >>= 1) mm = fmaxf(mm, __shfl_xor(mm, off));
      unsigned long long mx = __ballot(active && (mag == mm));
      if (mx == 0ULL) mx = __ballot(active); // degenerate (NaN) guard
      p = __ffsll(mx) - 1;
    }
    p &= 63;                                 // uniform (ballot-derived), valid lane

    bool isPiv = (r == p);
    pivmag = isPiv ? mag : pivmag;           // latch; log deferred to the end
    active = active && !isPiv;

    __half2 pivh = i2h(__builtin_amdgcn_readlane(h2i(a2[0]), p));
    float pr = __low2float(pivh);
    float pi = __high2float(pivh);
    float inv = __builtin_amdgcn_rcpf(fmaf(pr, pr, pi * pi));
    float fre = (fr0 * pr + fi0 * pi) * inv;
    float fim = (fi0 * pr - fr0 * pi) * inv;
    fre = active ? fre : 0.0f;               // pivot + retired lanes: shift-only
    fim = active ? fim : 0.0f;
    __half2 nfre2 = __float2half2_rn(-fre);                     // (-fre, -fre)
    __half2 fim2 = __halves2half2(__float2half_rn(fim),
                                  __float2half_rn(-fim));       // (fim, -fim)

    int rem = 63 - k;                        // remaining columns at slots 1..rem
#pragma unroll
    for (int ch = 0; ch < 8; ++ch) {
      if (ch * 8 < rem) {                    // uniform scalar guard, chunk=8
        int c0 = ch * 8 + 1;
        int Li[8];
#pragma unroll
        for (int e = 0; e < 8; ++e)          // batch: 8 readlanes (packed rows)
          Li[e] = __builtin_amdgcn_readlane(h2i(a2[c0 + e]), p);
#pragma unroll
        for (int e = 0; e < 8; ++e) {
          __half2 P = i2h(Li[e]);
          // (re',im') = (re,im) - fre*(lr,li) + fim*(li,-lr): 2 pk_fma
          // (__lowhigh2highlow folds into pk_fma op_sel -- r13 errata)
          __half2 tmp = __hfma2(nfre2, P, a2[c0 + e]);
          a2[c0 + e - 1] = __hfma2(fim2, __lowhigh2highlow(P), tmp);
        }
      }
    }
  }
  {
    float fr0 = __low2float(a2[0]);
    float fi0 = __high2float(a2[0]);
    if (active) pivmag = fmaf(fr0, fr0, fi0 * fi0);  // last surviving row
  }

  float logsum = 0.5f * __logf(pivmag);      // one log per lane; sum = logdet
#pragma unroll
  for (int off = 32; off > 0; off >>= 1) logsum += __shfl_xor(logsum, off);
  if (r == 0) atomicAdd(&logdet[b], weight * logsum);
}

// ---------------------------------------------------------------------------
extern "C" void kernel_launch(void* const* d_in, const int* in_sizes, int n_in,
                              void* d_out, int out_size, void* d_ws, size_t ws_size,
                              hipStream_t stream) {
  const float* conv_in = (const float*)d_in[0];   // [4,64,64,64]
  const float* K       = (const float*)d_in[1];   // [4,64,64,3,3]
  const float* bias    = (const float*)d_in[2];   // [4,64,1,1]
  float* out = (float*)d_out;                     // conv_out (1048576) ++ logdet (4)
  float* logdet = out + 1048576;

  hipMemsetAsync(logdet, 0, 4 * sizeof(float), stream);
  fused_kernel<<<dim3(2306), dim3(256), 0, stream>>>(conv_in, K, bias, out, logdet);
}